// Round 3
// baseline (298.649 us; speedup 1.0000x reference)
//
#include <hip/hip_runtime.h>
#include <hip/hip_bf16.h>

typedef __attribute__((ext_vector_type(8))) short short8;
typedef __attribute__((ext_vector_type(4))) float f32x4;
typedef unsigned short ushort_t;

namespace {

constexpr int H     = 128;
constexpr int E     = 1000000;
constexpr int NNODE = 100000;
constexpr int EB    = 256;                   // edges per tile
constexpr int NTILE = (E + EB - 1) / EB;     // 3907
constexpr int GRID  = 256;                   // persistent: 1 block per CU

// d_ws layout
constexpr size_t NB_OFF  = 0;                                  // bf16 nodes: 25.6 MB
constexpr size_t W1F_OFF = (size_t)NNODE * H * 2;
constexpr size_t W2F_OFF = W1F_OFF + 64 * 1024;
constexpr size_t WS_NEED = W2F_OFF + 16 * 1024;

__device__ __forceinline__ ushort_t f2bf(float x) {
    unsigned u = __float_as_uint(x);
    return (ushort_t)((u + 0x7FFFu + ((u >> 16) & 1u)) >> 16);
}
__device__ __forceinline__ int imin(int a, int b) { return a < b ? a : b; }

// ---- prep 1: node_embed fp32 -> bf16 table ----
__global__ void cvt_nodes(const float* __restrict__ src, ushort_t* __restrict__ dst, int n4) {
    int i = blockIdx.x * blockDim.x + threadIdx.x;
    int stride = gridDim.x * blockDim.x;
    for (; i < n4; i += stride) {
        float4 v = reinterpret_cast<const float4*>(src)[i];
        ushort4 o;
        o.x = f2bf(v.x); o.y = f2bf(v.y); o.z = f2bf(v.z); o.w = f2bf(v.w);
        reinterpret_cast<ushort4*>(dst)[i] = o;
    }
}

// ---- prep 2: W1/W2 -> bf16 MFMA B-fragment layout ----
__global__ void cvt_wfrag(const float* __restrict__ W1, const float* __restrict__ W2,
                          ushort_t* __restrict__ w1f, ushort_t* __restrict__ w2f) {
    int u = blockIdx.x, l = threadIdx.x;
    int lo = l & 15, hi = l >> 4;
    if (u < 64) {                       // W1: 8 K-steps x 8 N-tiles
        int s = u >> 3, n = u & 7;
#pragma unroll
        for (int j = 0; j < 8; ++j)
            w1f[(u * 64 + l) * 8 + j] = f2bf(W1[(s * 32 + hi * 8 + j) * 128 + n * 16 + lo]);
    } else {                            // W2: 4 K-steps x 4 N-tiles
        int u2 = u - 64;
        int s = u2 >> 2, n = u2 & 3;
#pragma unroll
        for (int j = 0; j < 8; ++j)
            w2f[(u2 * 64 + l) * 8 + j] = f2bf(W2[(s * 32 + hi * 8 + j) * 64 + n * 16 + lo]);
    }
}

// ---- main persistent kernel ----
struct SmemT {
    ushort_t w1f[32768];        // 64 KB
    ushort_t w2f[8192];         // 16 KB
    ushort_t hbuf[8][32 * 136]; // 68 KB per-wave h
    float    b1s[H], w1t0[H], w1t1[H], gs[H], bs[H];
    float    b2s[64], w3s[64];
};                              // 154,624 B

__global__ __launch_bounds__(512, 2)
void edge_mlp_mfma(const ushort_t* __restrict__ nb,
                   const ushort_t* __restrict__ w1fg,
                   const ushort_t* __restrict__ w2fg,
                   const int*      __restrict__ eidx,   // [2][E] int32
                   const float*    __restrict__ attr,   // [E][2]
                   const float*    __restrict__ W1,
                   const float*    __restrict__ b1,
                   const float*    __restrict__ gamma_,
                   const float*    __restrict__ beta_,
                   const float*    __restrict__ b2,
                   const float*    __restrict__ W3,
                   const float*    __restrict__ b3,
                   float*          __restrict__ out) {
    __shared__ SmemT sm;
    const int tid = threadIdx.x;
    const int bid = blockIdx.x;

    // ---- stage weights/params ONCE per block ----
    {
        const uint4* s1 = reinterpret_cast<const uint4*>(w1fg);
        uint4*       d1 = reinterpret_cast<uint4*>(sm.w1f);
#pragma unroll
        for (int i = 0; i < 8; ++i) d1[i * 512 + tid] = s1[i * 512 + tid];
        const uint4* s2 = reinterpret_cast<const uint4*>(w2fg);
        uint4*       d2 = reinterpret_cast<uint4*>(sm.w2f);
#pragma unroll
        for (int i = 0; i < 2; ++i) d2[i * 512 + tid] = s2[i * 512 + tid];
    }
    if (tid < 128) {
        sm.b1s[tid]  = b1[tid];
        sm.w1t0[tid] = W1[256 * H + tid];
        sm.w1t1[tid] = W1[257 * H + tid];
        sm.gs[tid]   = gamma_[tid];
        sm.bs[tid]   = beta_[tid];
        if (tid < 64) { sm.b2s[tid] = b2[tid]; sm.w3s[tid] = W3[tid]; }
    }
    __syncthreads();   // the only block-wide barrier

    const int wid  = tid >> 6;
    const int lane = tid & 63;
    const int lo   = lane & 15, hi = lane >> 4;
    const int ebl  = wid * 32;
    const int nk   = (bid < NTILE - 15 * GRID) ? 16 : 15;   // 67 blocks do 16 tiles

    ushort_t* hw = sm.hbuf[wid];

    float gv[8], bv[8];
#pragma unroll
    for (int n = 0; n < 8; ++n) { gv[n] = sm.gs[n * 16 + lo]; bv[n] = sm.bs[n * 16 + lo]; }
    float b2v[4], w3v[4];
#pragma unroll
    for (int n = 0; n < 4; ++n) { b2v[n] = sm.b2s[n * 16 + lo]; w3v[n] = sm.w3s[n * 16 + lo]; }
    const float b3s = b3[0];

    // ---- pipeline helpers ----
    auto load_idx = [&](int kk, int& ni0, int& nj0, int& ni1, int& nj1) {
        int t  = imin(kk, nk - 1);
        int eb = (bid + t * GRID) * EB + ebl;
        int e0 = imin(eb + lo, E - 1);
        int e1 = imin(eb + 16 + lo, E - 1);
        ni0 = eidx[e0]; nj0 = eidx[E + e0];
        ni1 = eidx[e1]; nj1 = eidx[E + e1];
    };
    auto gather = [&](short8 (&af)[2][8], int ni0, int nj0, int ni1, int nj1) {
#pragma unroll
        for (int s = 0; s < 4; ++s) {
            af[0][s]     = *reinterpret_cast<const short8*>(nb + (size_t)ni0 * H + s * 32 + hi * 8);
            af[0][4 + s] = *reinterpret_cast<const short8*>(nb + (size_t)nj0 * H + s * 32 + hi * 8);
            af[1][s]     = *reinterpret_cast<const short8*>(nb + (size_t)ni1 * H + s * 32 + hi * 8);
            af[1][4 + s] = *reinterpret_cast<const short8*>(nb + (size_t)nj1 * H + s * 32 + hi * 8);
        }
    };

    auto compute = [&](short8 (&af)[2][8], int k) {
        const int eb_t = (bid + k * GRID) * EB;
        const int ebw  = eb_t + ebl;

        // attr loads for THIS tile: issued now, consumed after GEMM1 (~700 cyc)
        float2 at[2][4];
#pragma unroll
        for (int mt = 0; mt < 2; ++mt)
#pragma unroll
            for (int r = 0; r < 4; ++r) {
                int e = imin(ebw + mt * 16 + hi * 4 + r, E - 1);
                at[mt][r] = *reinterpret_cast<const float2*>(attr + (size_t)e * 2);
            }

        // GEMM1: [32 edges] x [K=256] x [128 cols]
        f32x4 acc1[2][8];
        const f32x4 zero4 = {0.f, 0.f, 0.f, 0.f};
#pragma unroll
        for (int mt = 0; mt < 2; ++mt)
#pragma unroll
            for (int n = 0; n < 8; ++n) acc1[mt][n] = zero4;

#pragma unroll
        for (int s = 0; s < 8; ++s) {
#pragma unroll
            for (int n = 0; n < 8; ++n) {
                short8 bfv = *reinterpret_cast<const short8*>(sm.w1f + ((s * 8 + n) * 64 + lane) * 8);
                acc1[0][n] = __builtin_amdgcn_mfma_f32_16x16x32_bf16(af[0][s], bfv, acc1[0][n], 0, 0, 0);
                acc1[1][n] = __builtin_amdgcn_mfma_f32_16x16x32_bf16(af[1][s], bfv, acc1[1][n], 0, 0, 0);
            }
        }

        // + b1 + attr tail (fp32)
#pragma unroll
        for (int n = 0; n < 8; ++n) {
            int col = n * 16 + lo;
            float bb = sm.b1s[col], t0 = sm.w1t0[col], t1 = sm.w1t1[col];
#pragma unroll
            for (int mt = 0; mt < 2; ++mt)
#pragma unroll
                for (int r = 0; r < 4; ++r)
                    acc1[mt][n][r] += bb + at[mt][r].x * t0 + at[mt][r].y * t1;
        }

        // LayerNorm (16-lane xor reduce) + ReLU -> h (bf16, per-wave LDS)
#pragma unroll
        for (int mt = 0; mt < 2; ++mt) {
#pragma unroll
            for (int r = 0; r < 4; ++r) {
                float s1 = 0.f, s2 = 0.f;
#pragma unroll
                for (int n = 0; n < 8; ++n) { float x = acc1[mt][n][r]; s1 += x; s2 += x * x; }
#pragma unroll
                for (int off = 8; off >= 1; off >>= 1) {
                    s1 += __shfl_xor(s1, off);
                    s2 += __shfl_xor(s2, off);
                }
                float mean = s1 * (1.f / 128.f);
                float var  = s2 * (1.f / 128.f) - mean * mean;
                float rstd = rsqrtf(var + 1e-5f);
                int row = mt * 16 + hi * 4 + r;
#pragma unroll
                for (int n = 0; n < 8; ++n) {
                    float hx = fmaxf((acc1[mt][n][r] - mean) * rstd * gv[n] + bv[n], 0.f);
                    hw[row * 136 + n * 16 + lo] = f2bf(hx);
                }
            }
        }
        // wave-local LDS round trip: compiler-inserted lgkmcnt ordering suffices

        // GEMM2: [32 edges] x [K=128] x [64 cols]
        f32x4 acc2[2][4];
#pragma unroll
        for (int mt = 0; mt < 2; ++mt)
#pragma unroll
            for (int n = 0; n < 4; ++n) acc2[mt][n] = zero4;

#pragma unroll
        for (int s = 0; s < 4; ++s) {
            short8 af2_0 = *reinterpret_cast<const short8*>(hw + (lo)      * 136 + s * 32 + hi * 8);
            short8 af2_1 = *reinterpret_cast<const short8*>(hw + (16 + lo) * 136 + s * 32 + hi * 8);
#pragma unroll
            for (int n = 0; n < 4; ++n) {
                short8 bf2 = *reinterpret_cast<const short8*>(sm.w2f + ((s * 4 + n) * 64 + lane) * 8);
                acc2[0][n] = __builtin_amdgcn_mfma_f32_16x16x32_bf16(af2_0, bf2, acc2[0][n], 0, 0, 0);
                acc2[1][n] = __builtin_amdgcn_mfma_f32_16x16x32_bf16(af2_1, bf2, acc2[1][n], 0, 0, 0);
            }
        }

        // +b2, ReLU, dot W3, 16-lane reduce, +b3, store
#pragma unroll
        for (int mt = 0; mt < 2; ++mt)
#pragma unroll
            for (int r = 0; r < 4; ++r) {
                float part = 0.f;
#pragma unroll
                for (int n = 0; n < 4; ++n) {
                    float z = fmaxf(acc2[mt][n][r] + b2v[n], 0.f);
                    part = fmaf(z, w3v[n], part);
                }
#pragma unroll
                for (int off = 8; off >= 1; off >>= 1) part += __shfl_xor(part, off);
                if (lo == 0) {
                    int e = eb_t + ebl + mt * 16 + hi * 4 + r;
                    if (e < E) out[e] = part + b3s;
                }
            }
    };

    // ---- software pipeline: idx 2 ahead, gathers 1 ahead (ping-pong regs) ----
    short8 afA[2][8], afB[2][8];
    int ni0, nj0, ni1, nj1;

    load_idx(0, ni0, nj0, ni1, nj1);
    gather(afA, ni0, nj0, ni1, nj1);
    load_idx(1, ni0, nj0, ni1, nj1);

    int k = 0;
    while (true) {
        gather(afB, ni0, nj0, ni1, nj1);       // prefetch tile k+1
        load_idx(k + 2, ni0, nj0, ni1, nj1);   // indices for tile k+2
        compute(afA, k);
        ++k; if (k == nk) break;

        gather(afA, ni0, nj0, ni1, nj1);
        load_idx(k + 2, ni0, nj0, ni1, nj1);
        compute(afB, k);
        ++k; if (k == nk) break;
    }
}

} // namespace

extern "C" void kernel_launch(void* const* d_in, const int* in_sizes, int n_in,
                              void* d_out, int out_size, void* d_ws, size_t ws_size,
                              hipStream_t stream) {
    const float* node_embed = (const float*)d_in[0];
    const int*   eidx       = (const int*)  d_in[1];
    const float* attr       = (const float*)d_in[2];
    const float* W1         = (const float*)d_in[3];
    const float* b1         = (const float*)d_in[4];
    const float* gamma      = (const float*)d_in[5];
    const float* beta       = (const float*)d_in[6];
    const float* W2         = (const float*)d_in[7];
    const float* b2         = (const float*)d_in[8];
    const float* W3         = (const float*)d_in[9];
    const float* b3         = (const float*)d_in[10];
    float* out = (float*)d_out;

    if (ws_size < WS_NEED) return;

    char* ws = (char*)d_ws;
    ushort_t* nbf = (ushort_t*)(ws + NB_OFF);
    ushort_t* w1f = (ushort_t*)(ws + W1F_OFF);
    ushort_t* w2f = (ushort_t*)(ws + W2F_OFF);

    cvt_nodes<<<2048, 256, 0, stream>>>(node_embed, nbf, NNODE * H / 4);
    cvt_wfrag<<<80, 64, 0, stream>>>(W1, W2, w1f, w2f);
    edge_mlp_mfma<<<GRID, 512, 0, stream>>>(nbf, w1f, w2f, eidx, attr, W1, b1,
                                            gamma, beta, b2, W3, b3, out);
}

// Round 4
// 253.878 us; speedup vs baseline: 1.1764x; 1.1764x over previous
//
#include <hip/hip_runtime.h>
#include <hip/hip_bf16.h>

typedef __attribute__((ext_vector_type(8))) short short8;
typedef __attribute__((ext_vector_type(4))) float f32x4;
typedef unsigned short ushort_t;

namespace {

constexpr int H     = 128;
constexpr int E     = 1000000;
constexpr int NNODE = 100000;
constexpr int EB    = 256;                   // edges per tile (8 waves x 32)
constexpr int NTILE = (E + EB - 1) / EB;     // 3907
constexpr int GRID  = 256;                   // persistent: 1 block per CU

// d_ws layout
constexpr size_t NB_OFF  = 0;                                  // bf16 nodes: 25.6 MB
constexpr size_t W1F_OFF = (size_t)NNODE * H * 2;
constexpr size_t W1F_SZ  = 72 * 64 * 8 * 2;                    // 73728 B (K=288: 9 steps x 8 ntiles)
constexpr size_t W2F_OFF = W1F_OFF + W1F_SZ;
constexpr size_t W2F_SZ  = 20 * 64 * 8 * 2;                    // 20480 B (K=160: 5 steps x 4 ntiles)
constexpr size_t WS_NEED = W2F_OFF + W2F_SZ;

__device__ __forceinline__ ushort_t f2bf(float x) {
    unsigned u = __float_as_uint(x);
    return (ushort_t)((u + 0x7FFFu + ((u >> 16) & 1u)) >> 16);
}
__device__ __forceinline__ unsigned pkbf(float a, float b) {
    __hip_bfloat162 t = __float22bfloat162_rn(make_float2(a, b));
    return *reinterpret_cast<unsigned*>(&t);
}
__device__ __forceinline__ int imin(int a, int b) { return a < b ? a : b; }

union FragU { int4 i; short8 s; };

// ---- prep 1: node_embed fp32 -> bf16 table ----
__global__ void cvt_nodes(const float* __restrict__ src, ushort_t* __restrict__ dst, int n4) {
    int i = blockIdx.x * blockDim.x + threadIdx.x;
    int stride = gridDim.x * blockDim.x;
    for (; i < n4; i += stride) {
        float4 v = reinterpret_cast<const float4*>(src)[i];
        ushort4 o;
        o.x = f2bf(v.x); o.y = f2bf(v.y); o.z = f2bf(v.z); o.w = f2bf(v.w);
        reinterpret_cast<ushort4*>(dst)[i] = o;
    }
}

// ---- prep 2: W1ext (K=288, incl. attr rows + b1 row) / W2ext (K=160, incl. b2 row)
//      -> bf16 MFMA fragment layout: unit u, lane l holds M[k = s*32 + (l>>4)*8 + j][col = n*16 + (l&15)]
__global__ void cvt_wfrag(const float* __restrict__ W1, const float* __restrict__ b1,
                          const float* __restrict__ W2, const float* __restrict__ b2,
                          ushort_t* __restrict__ w1f, ushort_t* __restrict__ w2f) {
    int u = blockIdx.x, l = threadIdx.x;
    int lo = l & 15, hi = l >> 4;
    if (u < 72) {                       // W1ext: 9 K-steps x 8 N-tiles
        int s = u >> 3, n = u & 7, col = n * 16 + lo;
#pragma unroll
        for (int j = 0; j < 8; ++j) {
            int kk = s * 32 + hi * 8 + j;
            float v = (kk < 258) ? W1[kk * 128 + col]
                    : (kk == 258 ? b1[col] : 0.f);
            w1f[(u * 64 + l) * 8 + j] = f2bf(v);
        }
    } else {                            // W2ext: 5 K-steps x 4 N-tiles
        int u2 = u - 72;
        int s = u2 >> 2, n = u2 & 3, col = n * 16 + lo;
#pragma unroll
        for (int j = 0; j < 8; ++j) {
            int kk = s * 32 + hi * 8 + j;
            float v = (kk < 128) ? W2[kk * 64 + col]
                    : (kk == 128 ? b2[col] : 0.f);
            w2f[(u2 * 64 + l) * 8 + j] = f2bf(v);
        }
    }
}

// ---- main persistent kernel ----
struct SmemT {
    ushort_t w1f[36864];     // 73728 B
    ushort_t w2f[10240];     // 20480 B
    char     hbuf[65536];    // 8 waves x (2 mt x 16 edges x 256 B)
    float    gs[128], bs[128];
};                           // 160768 B

__global__ __launch_bounds__(512, 2)
void edge_mlp_mfma(const ushort_t* __restrict__ nb,
                   const ushort_t* __restrict__ w1fg,
                   const ushort_t* __restrict__ w2fg,
                   const int*      __restrict__ eidx,   // [2][E] int32
                   const float*    __restrict__ attr,   // [E][2]
                   const float*    __restrict__ gamma_,
                   const float*    __restrict__ beta_,
                   const float*    __restrict__ W3,
                   const float*    __restrict__ b3,
                   float*          __restrict__ out) {
    __shared__ SmemT sm;
    const int tid = threadIdx.x;
    const int bid = blockIdx.x;

    // ---- stage weights/params ONCE ----
    {
        const uint4* s1 = reinterpret_cast<const uint4*>(w1fg);
        uint4*       d1 = reinterpret_cast<uint4*>(sm.w1f);
#pragma unroll
        for (int i = 0; i < 9; ++i) d1[i * 512 + tid] = s1[i * 512 + tid];
        const uint4* s2 = reinterpret_cast<const uint4*>(w2fg);
        uint4*       d2 = reinterpret_cast<uint4*>(sm.w2f);
        for (int i = tid; i < 1280; i += 512) d2[i] = s2[i];
    }
    if (tid < 128) { sm.gs[tid] = gamma_[tid]; sm.bs[tid] = beta_[tid]; }
    __syncthreads();   // the only block-wide barrier

    const int wid = tid >> 6;
    const int lane = tid & 63;
    const int lo = lane & 15, hi = lane >> 4;
    const int ebl = wid * 32;
    const int nk = (bid < NTILE - 15 * GRID) ? 16 : 15;
    char* hb = sm.hbuf + wid * 8192;
    const int xsw = (lo & 7) << 4;
    const float2* attr2 = reinterpret_cast<const float2*>(attr);

    f32x4 w3v[4];
#pragma unroll
    for (int n2 = 0; n2 < 4; ++n2)
        w3v[n2] = *reinterpret_cast<const f32x4*>(W3 + n2 * 16 + hi * 4);
    const float b3s = b3[0];

    auto tb_of = [&](int k) { int t = k < nk ? k : nk - 1; return (bid + t * GRID) * EB + ebl; };
    auto gat = [&](short8 (&af)[2][4], int n0, int n1) {
#pragma unroll
        for (int s = 0; s < 4; ++s) {
            af[0][s] = *reinterpret_cast<const short8*>(nb + (size_t)n0 * H + s * 32 + hi * 8);
            af[1][s] = *reinterpret_cast<const short8*>(nb + (size_t)n1 * H + s * 32 + hi * 8);
        }
    };

    short8 aiC[2][4], aiN[2][4], ajC[2][4];
    int ji0, ji1, ii0n, ii1n;

    // ---- prologue ----
    {
        int tb = tb_of(0);
        int a = eidx[imin(tb + lo, E - 1)];
        int b = eidx[imin(tb + 16 + lo, E - 1)];
        gat(aiC, a, b);
        ji0 = eidx[E + imin(tb + lo, E - 1)];
        ji1 = eidx[E + imin(tb + 16 + lo, E - 1)];
        int tb1 = tb_of(1);
        ii0n = eidx[imin(tb1 + lo, E - 1)];
        ii1n = eidx[imin(tb1 + 16 + lo, E - 1)];
    }

    for (int k = 0; k < nk; ++k) {
        // gather node_j (tile k) and prefetch node_i (tile k+1)
        gat(ajC, ji0, ji1);
        gat(aiN, ii0n, ii1n);
        // indices for the future
        int jn0, jn1, in0, in1;
        {
            int tbj = tb_of(k + 1);
            jn0 = eidx[E + imin(tbj + lo, E - 1)];
            jn1 = eidx[E + imin(tbj + 16 + lo, E - 1)];
            int tbi = tb_of(k + 2);
            in0 = eidx[imin(tbi + lo, E - 1)];
            in1 = eidx[imin(tbi + 16 + lo, E - 1)];
        }
        const int tb = tb_of(k);
        // attr for this tile (only hi==0 lanes' values used)
        float2 av0 = attr2[imin(tb + lo, E - 1)];
        float2 av1 = attr2[imin(tb + 16 + lo, E - 1)];

        // ---- GEMM1 (swapped): acc[feat-tile][edge] over K=288 ----
        f32x4 acc1[2][8];
        const f32x4 zero4 = {0.f, 0.f, 0.f, 0.f};
#pragma unroll
        for (int mt = 0; mt < 2; ++mt)
#pragma unroll
            for (int n = 0; n < 8; ++n) acc1[mt][n] = zero4;

#pragma unroll
        for (int s = 0; s < 4; ++s)
#pragma unroll
            for (int n = 0; n < 8; ++n) {
                short8 wa = *reinterpret_cast<const short8*>(sm.w1f + ((s * 8 + n) * 64 + lane) * 8);
                acc1[0][n] = __builtin_amdgcn_mfma_f32_16x16x32_bf16(wa, aiC[0][s], acc1[0][n], 0, 0, 0);
                acc1[1][n] = __builtin_amdgcn_mfma_f32_16x16x32_bf16(wa, aiC[1][s], acc1[1][n], 0, 0, 0);
            }
#pragma unroll
        for (int s = 0; s < 4; ++s)
#pragma unroll
            for (int n = 0; n < 8; ++n) {
                short8 wa = *reinterpret_cast<const short8*>(sm.w1f + (((s + 4) * 8 + n) * 64 + lane) * 8);
                acc1[0][n] = __builtin_amdgcn_mfma_f32_16x16x32_bf16(wa, ajC[0][s], acc1[0][n], 0, 0, 0);
                acc1[1][n] = __builtin_amdgcn_mfma_f32_16x16x32_bf16(wa, ajC[1][s], acc1[1][n], 0, 0, 0);
            }
        {   // K-step 8: attr0, attr1, 1.0 (bias) rows
            FragU f0, f1;
            f0.i = make_int4(hi == 0 ? (int)pkbf(av0.x, av0.y) : 0, hi == 0 ? 0x3F80 : 0, 0, 0);
            f1.i = make_int4(hi == 0 ? (int)pkbf(av1.x, av1.y) : 0, hi == 0 ? 0x3F80 : 0, 0, 0);
#pragma unroll
            for (int n = 0; n < 8; ++n) {
                short8 wa = *reinterpret_cast<const short8*>(sm.w1f + ((64 + n) * 64 + lane) * 8);
                acc1[0][n] = __builtin_amdgcn_mfma_f32_16x16x32_bf16(wa, f0.s, acc1[0][n], 0, 0, 0);
                acc1[1][n] = __builtin_amdgcn_mfma_f32_16x16x32_bf16(wa, f1.s, acc1[1][n], 0, 0, 0);
            }
        }

        // ---- per edge-half: LN -> h(LDS, swizzled) -> GEMM2 -> dot W3 -> store ----
#pragma unroll
        for (int mt = 0; mt < 2; ++mt) {
            float s1 = 0.f, s2 = 0.f;
#pragma unroll
            for (int n = 0; n < 8; ++n)
#pragma unroll
                for (int r = 0; r < 4; ++r) {
                    float x = acc1[mt][n][r];
                    s1 += x; s2 = fmaf(x, x, s2);
                }
            s1 += __shfl_xor(s1, 16); s1 += __shfl_xor(s1, 32);
            s2 += __shfl_xor(s2, 16); s2 += __shfl_xor(s2, 32);
            float mean = s1 * (1.f / 128.f);
            float var  = s2 * (1.f / 128.f) - mean * mean;
            float rstd = rsqrtf(var + 1e-5f);

            char* hmt = hb + mt * 4096 + lo * 256;
#pragma unroll
            for (int n = 0; n < 8; ++n) {
                f32x4 gv = *reinterpret_cast<const f32x4*>(sm.gs + n * 16 + hi * 4);
                f32x4 bv = *reinterpret_cast<const f32x4*>(sm.bs + n * 16 + hi * 4);
                float h0 = fmaxf(fmaf((acc1[mt][n][0] - mean) * rstd, gv[0], bv[0]), 0.f);
                float h1 = fmaxf(fmaf((acc1[mt][n][1] - mean) * rstd, gv[1], bv[1]), 0.f);
                float h2 = fmaxf(fmaf((acc1[mt][n][2] - mean) * rstd, gv[2], bv[2]), 0.f);
                float h3 = fmaxf(fmaf((acc1[mt][n][3] - mean) * rstd, gv[3], bv[3]), 0.f);
                *reinterpret_cast<uint2*>(hmt + ((hi * 8 + n * 32) ^ xsw)) =
                    make_uint2(pkbf(h0, h1), pkbf(h2, h3));
            }

            // GEMM2 (swapped): acc2[col2-tile][edge] over K=160
            f32x4 a2[4];
#pragma unroll
            for (int n2 = 0; n2 < 4; ++n2) a2[n2] = zero4;
#pragma unroll
            for (int s = 0; s < 4; ++s) {
                short8 hf = *reinterpret_cast<const short8*>(hmt + ((s * 64 + hi * 16) ^ xsw));
#pragma unroll
                for (int n2 = 0; n2 < 4; ++n2) {
                    short8 wa = *reinterpret_cast<const short8*>(sm.w2f + ((s * 4 + n2) * 64 + lane) * 8);
                    a2[n2] = __builtin_amdgcn_mfma_f32_16x16x32_bf16(wa, hf, a2[n2], 0, 0, 0);
                }
            }
            {   // K-step 4: bias row (b2)
                FragU cf; cf.i = make_int4(hi == 0 ? 0x3F80 : 0, 0, 0, 0);
#pragma unroll
                for (int n2 = 0; n2 < 4; ++n2) {
                    short8 wa = *reinterpret_cast<const short8*>(sm.w2f + ((16 + n2) * 64 + lane) * 8);
                    a2[n2] = __builtin_amdgcn_mfma_f32_16x16x32_bf16(wa, cf.s, a2[n2], 0, 0, 0);
                }
            }

            // epilogue: relu, dot W3, cross-hi reduce, store
            float part = 0.f;
#pragma unroll
            for (int n2 = 0; n2 < 4; ++n2)
#pragma unroll
                for (int r = 0; r < 4; ++r)
                    part = fmaf(fmaxf(a2[n2][r], 0.f), w3v[n2][r], part);
            part += __shfl_xor(part, 16);
            part += __shfl_xor(part, 32);
            if (hi == 0) {
                int e = tb + mt * 16 + lo;
                if (e < E) out[e] = part + b3s;
            }
        }

        // rotate pipeline registers
#pragma unroll
        for (int s = 0; s < 4; ++s) { aiC[0][s] = aiN[0][s]; aiC[1][s] = aiN[1][s]; }
        ji0 = jn0; ji1 = jn1; ii0n = in0; ii1n = in1;
    }
}

} // namespace

extern "C" void kernel_launch(void* const* d_in, const int* in_sizes, int n_in,
                              void* d_out, int out_size, void* d_ws, size_t ws_size,
                              hipStream_t stream) {
    const float* node_embed = (const float*)d_in[0];
    const int*   eidx       = (const int*)  d_in[1];
    const float* attr       = (const float*)d_in[2];
    const float* W1         = (const float*)d_in[3];
    const float* b1         = (const float*)d_in[4];
    const float* gamma      = (const float*)d_in[5];
    const float* beta       = (const float*)d_in[6];
    const float* W2         = (const float*)d_in[7];
    const float* b2         = (const float*)d_in[8];
    const float* W3         = (const float*)d_in[9];
    const float* b3         = (const float*)d_in[10];
    float* out = (float*)d_out;

    if (ws_size < WS_NEED) return;

    char* ws = (char*)d_ws;
    ushort_t* nbf = (ushort_t*)(ws + NB_OFF);
    ushort_t* w1f = (ushort_t*)(ws + W1F_OFF);
    ushort_t* w2f = (ushort_t*)(ws + W2F_OFF);

    cvt_nodes<<<2048, 256, 0, stream>>>(node_embed, nbf, NNODE * H / 4);
    cvt_wfrag<<<92, 64, 0, stream>>>(W1, b1, W2, b2, w1f, w2f);
    edge_mlp_mfma<<<GRID, 512, 0, stream>>>(nbf, w1f, w2f, eidx, attr,
                                            gamma, beta, W3, b3, out);
}